// Round 1
// baseline (837.484 us; speedup 1.0000x reference)
//
#include <hip/hip_runtime.h>
#include <math.h>

#define CCH   512
#define HW    64
#define FXY   7
#define BINS  49                 // 7*7
#define POOL_LEN (CCH * BINS)    // 25088
#define NPOOLS 16
#define D_IN  (POOL_LEN * 6)     // 150528
#define NOUT  1024
#define KPB   147                // rows of W per k-block (147*1024 = 150528)
#define NKB   1024               // 4 blocks/CU -> 16 waves/CU
#define KBATCH 7                 // 147 = 21*7, loads staged 7-deep

// ---------------------------------------------------------------------------
// Region bounds for pool p:
//   p = 0        : scene (full 64x64)
//   p = 1..3     : human i = p-1
//   p = 4..15    : union(person i, obj j), i = (p-4)/4, j = (p-4)%4
// jnp.round == round-half-to-even == rintf (default rounding mode).
// ---------------------------------------------------------------------------
__device__ __forceinline__ void region_of(int p, const float* pb, const float* ob,
                                          float r0, float r1,
                                          int& x0, int& y0, int& x1, int& y1) {
    if (p == 0) { x0 = 0; y0 = 0; x1 = HW; y1 = HW; return; }
    if (p <= 3) {
        int i = p - 1;
        x0 = (int)rintf(pb[i * 4 + 0] * r0);
        y0 = (int)rintf(pb[i * 4 + 1] * r1);
        x1 = (int)rintf(pb[i * 4 + 2] * r0);
        y1 = (int)rintf(pb[i * 4 + 3] * r1);
        return;
    }
    int i = (p - 4) >> 2, j = (p - 4) & 3;
    int px0 = (int)rintf(pb[i * 4 + 0] * r0), py0 = (int)rintf(pb[i * 4 + 1] * r1);
    int px1 = (int)rintf(pb[i * 4 + 2] * r0), py1 = (int)rintf(pb[i * 4 + 3] * r1);
    int ox0 = (int)rintf(ob[j * 4 + 0] * r0), oy0 = (int)rintf(ob[j * 4 + 1] * r1);
    int ox1 = (int)rintf(ob[j * 4 + 2] * r0), oy1 = (int)rintf(ob[j * 4 + 3] * r1);
    x0 = min(px0, ox0); y0 = min(py0, oy0);
    x1 = max(px1, ox1); y1 = max(py1, oy1);
}

// One wave per (pool, channel). grid = (16, 128), block = 256 (4 waves).
__global__ __launch_bounds__(256) void pool_kernel(
        const float* __restrict__ feat, const float* __restrict__ pb,
        const float* __restrict__ ob, const float* __restrict__ ratio,
        float* __restrict__ pools) {
    int p    = blockIdx.x;
    int wv   = threadIdx.x >> 6;
    int lane = threadIdx.x & 63;
    int c    = blockIdx.y * 4 + wv;

    int x0, y0, x1, y1;
    region_of(p, pb, ob, ratio[0], ratio[1], x0, y0, x1, y1);
    int h = y1 - y0, w = x1 - x0;

    __shared__ float cm[4][FXY][HW];   // [wave][row-bin][x-rel] column maxes

    const float* f = feat + (size_t)c * (HW * HW);
    #pragma unroll
    for (int i = 0; i < FXY; ++i) {
        int rs = y0 + (i * h) / FXY;
        int re = y0 + ((i + 1) * h + FXY - 1) / FXY;   // ceil
        float m = -INFINITY;
        if (lane < w) {
            const float* fp = f + rs * HW + x0 + lane;
            for (int y = rs; y < re; ++y, fp += HW) m = fmaxf(m, *fp);
        }
        cm[wv][i][lane] = m;
    }
    __syncthreads();

    if (lane < BINS) {
        int i = lane / FXY, j = lane % FXY;
        int cs = (j * w) / FXY;
        int ce = ((j + 1) * w + FXY - 1) / FXY;        // ceil, relative to x0
        float m = -INFINITY;
        for (int x = cs; x < ce; ++x) m = fmaxf(m, cm[wv][i][x]);
        pools[(size_t)p * POOL_LEN + c * BINS + lane] = m;
    }
}

// K-split GEMV, atomic-free: block b computes partial[b][3][1024] over rows
// [b*147, (b+1)*147) of W. 1024 blocks (4/CU, 16 waves/CU) stream W.
// Loads are staged 7-deep into registers BEFORE any FMA so the compiler
// issues clustered global_load_dwordx4 (7 KB in flight per wave; 16 waves/CU
// covers ~900-cycle HBM latency with large margin).
// total[m][k] gathered from pools by segment:
//   s = k/25088: s==0 -> human[m] (pool 1+m); s in 1..4 -> union(m, s-1)
//   (pool 4 + m*4 + s-1); s==5 -> scene (pool 0, shared by all m).
__global__ __launch_bounds__(256) void gemv_kernel(
        const float* __restrict__ pools, const float* __restrict__ W,
        float* __restrict__ pf) {
    int b  = blockIdx.x;
    int k0 = b * KPB;
    __shared__ float t[3][KPB];
    for (int kk = threadIdx.x; kk < KPB; kk += 256) {
        int k = k0 + kk;
        int s = k / POOL_LEN, rr = k - s * POOL_LEN;
        #pragma unroll
        for (int m = 0; m < 3; ++m) {
            int pi = (s == 0) ? (1 + m) : ((s == 5) ? 0 : (4 + m * 4 + (s - 1)));
            t[m][kk] = pools[(size_t)pi * POOL_LEN + rr];
        }
    }
    __syncthreads();

    float acc[3][4] = {};
    const float4* Wp = (const float4*)(W + (size_t)k0 * NOUT) + threadIdx.x;
    #pragma unroll 1
    for (int kk = 0; kk < KPB; kk += KBATCH) {
        float4 w[KBATCH];
        #pragma unroll
        for (int u = 0; u < KBATCH; ++u)
            w[u] = Wp[(size_t)(kk + u) * (NOUT / 4)];
        #pragma unroll
        for (int u = 0; u < KBATCH; ++u) {
            float t0 = t[0][kk + u], t1 = t[1][kk + u], t2 = t[2][kk + u];
            acc[0][0] += t0 * w[u].x; acc[0][1] += t0 * w[u].y;
            acc[0][2] += t0 * w[u].z; acc[0][3] += t0 * w[u].w;
            acc[1][0] += t1 * w[u].x; acc[1][1] += t1 * w[u].y;
            acc[1][2] += t1 * w[u].z; acc[1][3] += t1 * w[u].w;
            acc[2][0] += t2 * w[u].x; acc[2][1] += t2 * w[u].y;
            acc[2][2] += t2 * w[u].z; acc[2][3] += t2 * w[u].w;
        }
    }
    // coalesced partial store: pf[b][m][n0..n0+3]
    #pragma unroll
    for (int m = 0; m < 3; ++m) {
        ((float4*)(pf + (size_t)b * (3 * NOUT) + m * NOUT))[threadIdx.x] =
            make_float4(acc[m][0], acc[m][1], acc[m][2], acc[m][3]);
    }
}

// Sum 1024 partials per output, add bias. 48 blocks x 256 threads; block
// handles 64 consecutive outputs, 4 wave-groups each sum 256 of the 1024
// b-slices with 8 independent accumulators (8 loads in flight).
__global__ __launch_bounds__(256) void reduce_kernel(
        const float* __restrict__ pf, const float* __restrict__ bias,
        float* __restrict__ out) {
    int o0 = blockIdx.x * 64;          // 48 blocks cover 3072 outputs
    int lo = threadIdx.x & 63;
    int g  = threadIdx.x >> 6;         // 0..3: b-range quarter (256 each)
    const float* p = pf + (size_t)(g * 256) * (3 * NOUT) + o0 + lo;
    float s[8] = {};
    #pragma unroll 1
    for (int i = 0; i < 256; i += 8) {
        #pragma unroll
        for (int u = 0; u < 8; ++u)
            s[u] += p[(size_t)(i + u) * (3 * NOUT)];
    }
    float tot_g = ((s[0] + s[1]) + (s[2] + s[3])) + ((s[4] + s[5]) + (s[6] + s[7]));
    __shared__ float sm[4][64];
    sm[g][lo] = tot_g;
    __syncthreads();
    if (g == 0) {
        int o = o0 + lo;
        float tot = (sm[0][lo] + sm[1][lo]) + (sm[2][lo] + sm[3][lo]);
        out[o] = bias[o & (NOUT - 1)] + tot;
    }
}

extern "C" void kernel_launch(void* const* d_in, const int* in_sizes, int n_in,
                              void* d_out, int out_size, void* d_ws, size_t ws_size,
                              hipStream_t stream) {
    const float* feature = (const float*)d_in[0];   // [1,512,64,64]
    const float* pb      = (const float*)d_in[1];   // [3,4]
    const float* ob      = (const float*)d_in[2];   // [4,4]
    const float* ratio   = (const float*)d_in[3];   // [2]
    const float* W       = (const float*)d_in[4];   // [150528,1024]
    const float* bias    = (const float*)d_in[5];   // [1024]
    float* out   = (float*)d_out;                   // [3,1024]
    float* pools = (float*)d_ws;                    // 16*25088 floats = 1.6 MB
    float* pf    = pools + (size_t)NPOOLS * POOL_LEN;  // 1024*3072 floats = 12.6 MB

    hipLaunchKernelGGL(pool_kernel, dim3(NPOOLS, CCH / 4), dim3(256), 0, stream,
                       feature, pb, ob, ratio, pools);
    hipLaunchKernelGGL(gemv_kernel, dim3(NKB), dim3(256), 0, stream,
                       pools, W, pf);
    hipLaunchKernelGGL(reduce_kernel, dim3(3 * NOUT / 64), dim3(256), 0, stream,
                       pf, bias, out);
}